// Round 5
// baseline (7911.662 us; speedup 1.0000x reference)
//
#include <hip/hip_runtime.h>
#include <hip/hip_fp16.h>

#define BATCH 32
#define SEQ   1024
#define DIM   512

typedef _Float16 f16x8 __attribute__((ext_vector_type(8)));
typedef float    f32x4 __attribute__((ext_vector_type(4)));
typedef unsigned int u32x4 __attribute__((ext_vector_type(4)));

union UU4 { uint4 s; u32x4 v; };

static __device__ __forceinline__ float tanh_fast(float x) {
    float e = __expf(2.0f * x);
    return 1.0f - 2.0f / (e + 1.0f);
}

// Barrier draining only LDS ops; global loads/stores stay in flight.
// h is exchanged only through LDS, so lgkmcnt(0) is the full requirement.
#define LDS_BARRIER() asm volatile("s_waitcnt lgkmcnt(0)\n\ts_barrier" ::: "memory")

// ---------------------------------------------------------------------------
// Pack a 512x512 fp32 row-major W into fp16 MFMA B-fragment layout:
//   Wp[((k>>5)*512 + n)*32 + ((k>>3)&3)*8 + (k&7)] = W[k][n]
// ---------------------------------------------------------------------------
__global__ void pack_w(const float* __restrict__ W, __half* __restrict__ Wp) {
    int id = blockIdx.x * blockDim.x + threadIdx.x;   // 0 .. 262143
    int n = id & 511;
    int k = id >> 9;
    Wp[((k >> 5) * 512 + n) * 32 + ((k >> 3) & 3) * 8 + (k & 7)] = __float2half(W[k * 512 + n]);
}

// ---------------------------------------------------------------------------
// Kernel 1 (v3, unchanged): xw = x @ W_xh + b. Grid (2, 512): 64 rows x 256
// cols per block, acc[16]. Measured rest-of-total (pack+gemm) = 169 us.
// ---------------------------------------------------------------------------
__global__ __launch_bounds__(256) void gemm_xw(const float* __restrict__ X,
                                               const __half* __restrict__ Wp,
                                               const float* __restrict__ bias,
                                               float* __restrict__ out) {
    const int nb   = blockIdx.x;          // 0..1   (256-col half)
    const int mb   = blockIdx.y;          // 0..511 (64-row stripe)
    const int lane = threadIdx.x & 63;
    const int wave = threadIdx.x >> 6;
    const int q    = lane >> 4;
    const int r16  = lane & 15;
    const int row  = mb * 64 + wave * 16 + r16;

    const float4* Xf4  = (const float4*)X;
    const uint4*  WpU4 = (const uint4*)Wp;

    f32x4 acc[16];
    #pragma unroll
    for (int nt = 0; nt < 16; ++nt) acc[nt] = (f32x4){0.f, 0.f, 0.f, 0.f};

    #pragma unroll 2
    for (int kb = 0; kb < 16; ++kb) {
        float4 a0 = Xf4[row * 128 + kb * 8 + q * 2];
        float4 a1 = Xf4[row * 128 + kb * 8 + q * 2 + 1];
        f16x8 af;
        af[0] = (_Float16)a0.x; af[1] = (_Float16)a0.y;
        af[2] = (_Float16)a0.z; af[3] = (_Float16)a0.w;
        af[4] = (_Float16)a1.x; af[5] = (_Float16)a1.y;
        af[6] = (_Float16)a1.z; af[7] = (_Float16)a1.w;
        #pragma unroll
        for (int nt = 0; nt < 16; ++nt) {
            int col = nb * 256 + nt * 16 + r16;
            UU4 tmp; tmp.s = WpU4[(kb * 512 + col) * 4 + q];
            acc[nt] = __builtin_amdgcn_mfma_f32_16x16x32_f16(
                af, __builtin_bit_cast(f16x8, tmp.v), acc[nt], 0, 0, 0);
        }
    }

    const int rbase = mb * 64 + wave * 16 + q * 4;
    #pragma unroll
    for (int nt = 0; nt < 16; ++nt) {
        int col = nb * 256 + nt * 16 + r16;
        float bv = bias[col];
        #pragma unroll
        for (int rr = 0; rr < 4; ++rr) {
            out[(size_t)(rbase + rr) * 512 + col] = acc[nt][rr] + bv;
        }
    }
}

// ---------------------------------------------------------------------------
// Kernel 2 (v6): BATCHED recurrence. 2 blocks x 16 batches, 512 threads
// (8 waves = 2/SIMD). The 16 MFMA M-rows now hold 16 DIFFERENT batches'
// h vectors (previous design replicated one h 16x -> 15/16 wasted MFMA).
// Per-SIMD MFMA: 128 x 4.85 = ~621 cyc/step for 16 real matvecs.
//
// h: double-buffered LDS tile [16][512] f16, XOR-swizzled rows
//   (byte-in-row ^= (batch&7)<<4) -> the 16-rows-same-col b128 A-read is
//   bank-minimum; b16 h-writes ~4-way on 128 B (cheap).
// W_hh: fully register-resident, 64 frags/wave = 48 "+a" + 16 "+v"
//   (the proven pin budget; R4 showed >48 AGPR pins = copy storm).
// A-frag map (16x16x32): lane l elem j = A[row=l&15][k=(l>>4)*8+j];
// C map (m89): col=lane&15, row=4q+reg -> thread owns batches 4q..4q+3
//   x cols {w*64+nt*16+r16}.
// xw: 16 dword loads at step top (consumed ~1300 cyc later); 16 dword
//   stores ride vmcnt past the lgkm-only barrier.
// ---------------------------------------------------------------------------
__global__ __launch_bounds__(512, 2) void rnn_rec(const uint4* __restrict__ Wp4,
                                                  float* __restrict__ out) {
    __shared__ __align__(16) char smem[32768];   // 2 x [16][512] f16, swizzled

    const int g    = blockIdx.x;       // batch group: batches g*16 .. g*16+15
    const int t    = threadIdx.x;      // 0..511
    const int lane = t & 63;
    const int w    = t >> 6;           // wave 0..7: cols [w*64, w*64+64)
    const int q    = lane >> 4;        // 0..3
    const int r16  = lane & 15;

    // ---- W_hh fragments: wave w needs 4 N-tiles x 16 kb = 64 frags ----
    u32x4 Bf[64];
    #pragma unroll
    for (int kb = 0; kb < 16; ++kb) {
        #pragma unroll
        for (int nt = 0; nt < 4; ++nt) {
            int col = w * 64 + nt * 16 + r16;
            UU4 tmp; tmp.s = Wp4[(kb * 512 + col) * 4 + q];
            Bf[kb * 4 + nt] = tmp.v;
        }
    }
    #pragma unroll
    for (int i = 0; i < 48; ++i) asm volatile("" : "+a"(Bf[i]));
    #pragma unroll
    for (int i = 48; i < 64; ++i) asm volatile("" : "+v"(Bf[i]));

    const int swz  = (r16 & 7) << 4;       // read-side swizzle (batch = r16)
    const int wcol = w * 128 + r16 * 2;    // write-side in-row byte base

    // Global row pointers for batches 4q+rr at column base w*64+r16.
    float* p0 = out + (size_t)(g * 16 + 4 * q) * (SEQ * DIM) + (w * 64 + r16);
    float* p1 = p0 + (size_t)SEQ * DIM;
    float* p2 = p1 + (size_t)SEQ * DIM;
    float* p3 = p2 + (size_t)SEQ * DIM;

    float xw[16];   // xw in-flight; holds h after tail (static-indexed only)

    // ---- step 0: h0 = tanh(xw0) ----
    #pragma unroll
    for (int nt = 0; nt < 4; ++nt) {
        xw[0 + nt] = p0[nt * 16];  xw[4 + nt] = p1[nt * 16];
        xw[8 + nt] = p2[nt * 16];  xw[12 + nt] = p3[nt * 16];
    }
    #pragma unroll
    for (int i = 0; i < 16; ++i) xw[i] = tanh_fast(xw[i]);
    #pragma unroll
    for (int nt = 0; nt < 4; ++nt) {
        p0[nt * 16] = xw[0 + nt];  p1[nt * 16] = xw[4 + nt];
        p2[nt * 16] = xw[8 + nt];  p3[nt * 16] = xw[12 + nt];
    }
    #pragma unroll
    for (int rr = 0; rr < 4; ++rr) {
        const int bt  = 4 * q + rr;
        const int bsw = (bt & 7) << 4;
        #pragma unroll
        for (int nt = 0; nt < 4; ++nt) {
            *(__half*)(smem + bt * 1024 + ((wcol + nt * 32) ^ bsw)) =
                __float2half(xw[rr * 4 + nt]);
        }
    }
    p0 += DIM; p1 += DIM; p2 += DIM; p3 += DIM;
    LDS_BARRIER();

    #pragma unroll 1
    for (int step = 1; step < SEQ; ++step) {
        // xw loads for this step (consumed after the MFMA block).
        #pragma unroll
        for (int nt = 0; nt < 4; ++nt) {
            xw[0 + nt] = p0[nt * 16];  xw[4 + nt] = p1[nt * 16];
            xw[8 + nt] = p2[nt * 16];  xw[12 + nt] = p3[nt * 16];
        }

        const int rbuf = ((step & 1) ^ 1) << 14;   // read h_{t-1}
        const int wbuf = (step & 1) << 14;         // write h_t

        f32x4 m0 = {0.f,0.f,0.f,0.f}, m1 = {0.f,0.f,0.f,0.f};
        f32x4 m2 = {0.f,0.f,0.f,0.f}, m3 = {0.f,0.f,0.f,0.f};

        #pragma unroll
        for (int kb = 0; kb < 16; ++kb) {
            f16x8 af = *(const f16x8*)(smem + rbuf + r16 * 1024 +
                                       ((q * 16 + kb * 64) ^ swz));
            m0 = __builtin_amdgcn_mfma_f32_16x16x32_f16(
                af, __builtin_bit_cast(f16x8, Bf[kb * 4 + 0]), m0, 0, 0, 0);
            m1 = __builtin_amdgcn_mfma_f32_16x16x32_f16(
                af, __builtin_bit_cast(f16x8, Bf[kb * 4 + 1]), m1, 0, 0, 0);
            m2 = __builtin_amdgcn_mfma_f32_16x16x32_f16(
                af, __builtin_bit_cast(f16x8, Bf[kb * 4 + 2]), m2, 0, 0, 0);
            m3 = __builtin_amdgcn_mfma_f32_16x16x32_f16(
                af, __builtin_bit_cast(f16x8, Bf[kb * 4 + 3]), m3, 0, 0, 0);
        }

        // Tail: h = tanh(m + xw); store to out; store f16 h to LDS[wbuf].
        #pragma unroll
        for (int rr = 0; rr < 4; ++rr) {
            const int bt  = 4 * q + rr;
            const int bsw = (bt & 7) << 4;
            float h0 = tanh_fast(m0[rr] + xw[rr * 4 + 0]);
            float h1 = tanh_fast(m1[rr] + xw[rr * 4 + 1]);
            float h2 = tanh_fast(m2[rr] + xw[rr * 4 + 2]);
            float h3 = tanh_fast(m3[rr] + xw[rr * 4 + 3]);
            float* p = (rr == 0 ? p0 : rr == 1 ? p1 : rr == 2 ? p2 : p3);
            p[0]  = h0; p[16] = h1; p[32] = h2; p[48] = h3;
            *(__half*)(smem + wbuf + bt * 1024 + ((wcol +  0) ^ bsw)) = __float2half(h0);
            *(__half*)(smem + wbuf + bt * 1024 + ((wcol + 32) ^ bsw)) = __float2half(h1);
            *(__half*)(smem + wbuf + bt * 1024 + ((wcol + 64) ^ bsw)) = __float2half(h2);
            *(__half*)(smem + wbuf + bt * 1024 + ((wcol + 96) ^ bsw)) = __float2half(h3);
            xw[rr * 4 + 0] = h0; xw[rr * 4 + 1] = h1;
            xw[rr * 4 + 2] = h2; xw[rr * 4 + 3] = h3;
        }
        p0 += DIM; p1 += DIM; p2 += DIM; p3 += DIM;
        LDS_BARRIER();
    }

    // h_final (f32, full precision from the last tail).
    #pragma unroll
    for (int rr = 0; rr < 4; ++rr) {
        float* hp = out + (size_t)BATCH * SEQ * DIM +
                    (size_t)(g * 16 + 4 * q + rr) * DIM + (w * 64 + r16);
        #pragma unroll
        for (int nt = 0; nt < 4; ++nt) hp[nt * 16] = xw[rr * 4 + nt];
    }
}

extern "C" void kernel_launch(void* const* d_in, const int* in_sizes, int n_in,
                              void* d_out, int out_size, void* d_ws, size_t ws_size,
                              hipStream_t stream) {
    const float* X    = (const float*)d_in[0];   // [32,1024,512] fp32
    const float* Wxh  = (const float*)d_in[1];   // [512,512] fp32
    const float* Whh  = (const float*)d_in[2];   // [512,512] fp32
    const float* bias = (const float*)d_in[3];   // [512] fp32
    float* out = (float*)d_out;

    __half* WpXh = (__half*)d_ws;                          // 512 KB @ 0
    __half* WpHh = (__half*)((char*)d_ws + (512u << 10));  // 512 KB @ 512K

    pack_w<<<512, 512, 0, stream>>>(Wxh, WpXh);
    pack_w<<<512, 512, 0, stream>>>(Whh, WpHh);
    gemm_xw<<<dim3(2, 512), 256, 0, stream>>>(X, WpXh, bias, out);
    rnn_rec<<<2, 512, 0, stream>>>((const uint4*)WpHh, out);
}

// Round 7
// 1475.475 us; speedup vs baseline: 5.3621x; 5.3621x over previous
//
#include <hip/hip_runtime.h>
#include <hip/hip_fp16.h>

#define BATCH 32
#define SEQ   1024
#define DIM   512

typedef _Float16 f16x8 __attribute__((ext_vector_type(8)));
typedef float    f32x4 __attribute__((ext_vector_type(4)));
typedef unsigned int u32x4 __attribute__((ext_vector_type(4)));

union UU4 { uint4 s; u32x4 v; };

static __device__ __forceinline__ float tanh_fast(float x) {
    float e = __expf(2.0f * x);
    return 1.0f - 2.0f / (e + 1.0f);
}

// ---------------------------------------------------------------------------
// Pack a 512x512 fp32 row-major W into fp16 MFMA B-fragment layout:
//   Wp[((k>>5)*512 + n)*32 + ((k>>3)&3)*8 + (k&7)] = W[k][n]
// ---------------------------------------------------------------------------
__global__ void pack_w(const float* __restrict__ W, __half* __restrict__ Wp) {
    int id = blockIdx.x * blockDim.x + threadIdx.x;   // 0 .. 262143
    int n = id & 511;
    int k = id >> 9;
    Wp[((k >> 5) * 512 + n) * 32 + ((k >> 3) & 3) * 8 + (k & 7)] = __float2half(W[k * 512 + n]);
}

// ---------------------------------------------------------------------------
// Kernel 1 (v3, proven: rest-of-total 169 us in R3): xw = x @ W_xh + b.
// Grid (2, 512): 64 rows x 256 cols per block, acc[16] f32x4 = 64 VGPRs.
// X re-read 2x (vs 8x in the original (8,512) grid).
// ---------------------------------------------------------------------------
__global__ __launch_bounds__(256) void gemm_xw(const float* __restrict__ X,
                                               const __half* __restrict__ Wp,
                                               const float* __restrict__ bias,
                                               float* __restrict__ out) {
    const int nb   = blockIdx.x;          // 0..1   (256-col half)
    const int mb   = blockIdx.y;          // 0..511 (64-row stripe)
    const int lane = threadIdx.x & 63;
    const int wave = threadIdx.x >> 6;
    const int q    = lane >> 4;
    const int r16  = lane & 15;
    const int row  = mb * 64 + wave * 16 + r16;

    const float4* Xf4  = (const float4*)X;
    const uint4*  WpU4 = (const uint4*)Wp;

    f32x4 acc[16];
    #pragma unroll
    for (int nt = 0; nt < 16; ++nt) acc[nt] = (f32x4){0.f, 0.f, 0.f, 0.f};

    #pragma unroll 2
    for (int kb = 0; kb < 16; ++kb) {
        float4 a0 = Xf4[row * 128 + kb * 8 + q * 2];
        float4 a1 = Xf4[row * 128 + kb * 8 + q * 2 + 1];
        f16x8 af;
        af[0] = (_Float16)a0.x; af[1] = (_Float16)a0.y;
        af[2] = (_Float16)a0.z; af[3] = (_Float16)a0.w;
        af[4] = (_Float16)a1.x; af[5] = (_Float16)a1.y;
        af[6] = (_Float16)a1.z; af[7] = (_Float16)a1.w;
        #pragma unroll
        for (int nt = 0; nt < 16; ++nt) {
            int col = nb * 256 + nt * 16 + r16;
            UU4 tmp; tmp.s = WpU4[(kb * 512 + col) * 4 + q];
            acc[nt] = __builtin_amdgcn_mfma_f32_16x16x32_f16(
                af, __builtin_bit_cast(f16x8, tmp.v), acc[nt], 0, 0, 0);
        }
    }

    const int rbase = mb * 64 + wave * 16 + q * 4;
    #pragma unroll
    for (int nt = 0; nt < 16; ++nt) {
        int col = nb * 256 + nt * 16 + r16;
        float bv = bias[col];
        #pragma unroll
        for (int rr = 0; rr < 4; ++rr) {
            out[(size_t)(rbase + rr) * 512 + col] = acc[nt][rr] + bv;
        }
    }
}

// ---------------------------------------------------------------------------
// Kernel 2: recurrence — VERBATIM the R1-v2 kernel (harness-verified,
// 1309 us, MfmaUtil 8.37 = 67% of active-CU MFMA pipe). 512 threads =
// 8 waves = 2 waves/SIMD. Wave w owns cols [w*64, w*64+64): 4 N-tiles x
// 16 k-blocks = 64 MFMA/step. B (W_hh): kb 0..11 register-resident
// (48 uint4 pinned to AGPR — the ONLY pin budget proven correct in this
// structure; 56/64-frag variants miscompiled or copy-stormed in R4/R6),
// kb 12..15 streamed from a 128 KB LDS image (stride-1 ds_read_b128,
// conflict-free). __syncthreads (not the lgkm-only barrier): measured
// equal (1309 vs 1321) and carries zero reorder risk.
// ---------------------------------------------------------------------------
__global__ __launch_bounds__(512, 2) void rnn_rec(const uint4* __restrict__ Wp4,
                                                  float* __restrict__ out) {
    extern __shared__ char smem[];
    uint4*  LBS = (uint4*)smem;                 // 8192 uint4 = 128 KB (kb 12..15)
    __half* hb  = (__half*)(smem + 131072);     // 2 x 512 halves (double buffer)

    const int b    = blockIdx.x;
    const int t    = threadIdx.x;    // 0..511
    const int lane = t & 63;
    const int w    = t >> 6;         // wave 0..7: owns cols [w*64, w*64+64)
    const int q    = lane >> 4;      // quad 0..3 (== this thread's N-tile)
    const int r16  = lane & 15;

    // Stage streamed B-fragments (k-blocks 12..15) into LDS.
    // Read layout: LBS[(s*4 + nt)*512 + t] -> stride-1 across the wave,
    // conflict-free ds_read_b128. Each thread stages its own 16 words.
    #pragma unroll
    for (int j = 0; j < 16; ++j) {
        int kb  = 12 + (j >> 2);
        int col = w * 64 + (j & 3) * 16 + r16;
        LBS[j * 512 + t] = Wp4[(kb * 512 + col) * 4 + q];
    }

    // Resident B-fragments: k-blocks 0..11 x 4 N-tiles = 48 uint4 / lane,
    // pinned to AGPRs to keep the VGPR file free for VALU work.
    u32x4 Bf[48];
    #pragma unroll
    for (int kb = 0; kb < 12; ++kb) {
        #pragma unroll
        for (int nt = 0; nt < 4; ++nt) {
            int col = w * 64 + nt * 16 + r16;
            UU4 tmp; tmp.s = Wp4[(kb * 512 + col) * 4 + q];
            Bf[kb * 4 + nt] = tmp.v;
        }
    }
    #pragma unroll
    for (int i = 0; i < 48; ++i) asm volatile("" : "+a"(Bf[i]));

    float* orow = out + (size_t)b * SEQ * DIM;
    const int c = w * 64 + q * 16 + r16;   // this thread's single output col

    // Step 0: h = tanh(xw).
    float xw = orow[c];
    float h  = tanh_fast(xw);
    orow[c] = h;
    hb[c] = __float2half(h);
    xw = orow[DIM + c];                    // prefetch step 1's xw
    __syncthreads();

    #pragma unroll 1
    for (int step = 1; step < SEQ; ++step) {
        orow += DIM;
        const __half* ha = hb + (((step & 1) ^ 1) << 9);   // h_{t-1}

        f32x4 m[4];
        #pragma unroll
        for (int i = 0; i < 4; ++i) m[i] = (f32x4){0.f, 0.f, 0.f, 0.f};

        // Streamed k-blocks first (LDS reads fill the pipe while MFMAs start).
        #pragma unroll
        for (int s = 0; s < 4; ++s) {
            f16x8 af = *(const f16x8*)(ha + (12 + s) * 32 + q * 8);
            #pragma unroll
            for (int nt = 0; nt < 4; ++nt) {
                UU4 tmp; tmp.s = LBS[(s * 4 + nt) * 512 + t];
                m[nt] = __builtin_amdgcn_mfma_f32_16x16x32_f16(
                    af, __builtin_bit_cast(f16x8, tmp.v), m[nt], 0, 0, 0);
            }
        }
        // Resident k-blocks.
        #pragma unroll
        for (int kb = 0; kb < 12; ++kb) {
            f16x8 af = *(const f16x8*)(ha + kb * 32 + q * 8);
            #pragma unroll
            for (int nt = 0; nt < 4; ++nt) {
                m[nt] = __builtin_amdgcn_mfma_f32_16x16x32_f16(
                    af, __builtin_bit_cast(f16x8, Bf[kb * 4 + nt]), m[nt], 0, 0, 0);
            }
        }

        // All acc rows equal (replicated A): tile q, reg 0 holds col c.
        float v = (q == 0 ? m[0][0] : q == 1 ? m[1][0] : q == 2 ? m[2][0] : m[3][0]) + xw;
        h = tanh_fast(v);

        orow[c] = h;
        __half* hw = hb + ((step & 1) << 9);
        hw[c] = __float2half(h);
        // Prefetch next xw (step 1023 reads into the h_final region: in-bounds,
        // value unused).
        xw = orow[DIM + c];
        __syncthreads();
    }

    float* hf = out + (size_t)BATCH * SEQ * DIM + (size_t)b * DIM;
    hf[c] = h;
}

extern "C" void kernel_launch(void* const* d_in, const int* in_sizes, int n_in,
                              void* d_out, int out_size, void* d_ws, size_t ws_size,
                              hipStream_t stream) {
    const float* X    = (const float*)d_in[0];   // [32,1024,512] fp32
    const float* Wxh  = (const float*)d_in[1];   // [512,512] fp32
    const float* Whh  = (const float*)d_in[2];   // [512,512] fp32
    const float* bias = (const float*)d_in[3];   // [512] fp32
    float* out = (float*)d_out;

    __half* WpXh = (__half*)d_ws;                          // 512 KB @ 0
    __half* WpHh = (__half*)((char*)d_ws + (512u << 10));  // 512 KB @ 512K

    (void)hipFuncSetAttribute((const void*)rnn_rec,
                              hipFuncAttributeMaxDynamicSharedMemorySize, 133120);

    pack_w<<<512, 512, 0, stream>>>(Wxh, WpXh);
    pack_w<<<512, 512, 0, stream>>>(Whh, WpHh);
    gemm_xw<<<dim3(2, 512), 256, 0, stream>>>(X, WpXh, bias, out);
    rnn_rec<<<BATCH, 512, 133120, stream>>>((const uint4*)WpHh, out);
}